// Round 6
// baseline (242.569 us; speedup 1.0000x reference)
//
#include <hip/hip_runtime.h>
#include <hip/hip_fp16.h>

// NNUE forward, round 6 = round 4 (known-green through all harness phases)
//  + non-temporal hints on single-use traffic (x loads, out stores, emb reads)
//    so the fp16 table keeps per-XCD L2 residency (tab 3.8 MB vs 4 MB L2;
//    x streams 8 MB/launch and was evicting it)
//  + __threadfence() device-release at end of stage (cross-XCD visibility
//    hardening for the d_ws staging writes; round-5 post-timing divergence
//    was staging-state related).
// Round-5's deeper gather pipeline is intentionally reverted: rounds 3->4->5
// proved the gather is concurrency-saturated (occupancy- and ILP-neutral).

#define STR2 33

using h2  = _Float16 __attribute__((ext_vector_type(2)));
using h4  = _Float16 __attribute__((ext_vector_type(4)));
using h8v = _Float16 __attribute__((ext_vector_type(8)));
using f4  = float __attribute__((ext_vector_type(4)));

union H8 { h8v v; h2 h[4]; };

__device__ __forceinline__ float frelu(float v) { return v > 0.f ? v : 0.f; }

__device__ __forceinline__ h2 h2relu(h2 v) {
    h2 r;
    r[0] = v[0] > (_Float16)0 ? v[0] : (_Float16)0;
    r[1] = v[1] > (_Float16)0 ? v[1] : (_Float16)0;
    return r;
}

// ---- staging: fp32->fp16 table; last block packs the weights ----
__global__ __launch_bounds__(256) void stage(
    const float* __restrict__ emb, _Float16* __restrict__ tab,
    const float* __restrict__ w2, const float* __restrict__ w3,
    const float* __restrict__ w4,
    _Float16* __restrict__ w2p, h2* __restrict__ w3p, h2* __restrict__ w4p,
    int n4) {
    if ((int)blockIdx.x == (int)gridDim.x - 1) {
        const int i = threadIdx.x;
        for (int e = i; e < 32 * 128; e += 256) w2p[e] = (_Float16)w2[e];
        for (int p = i; p < 32 * 32; p += 256) {
            const int o = p >> 5, j = p & 31;
            h2 c; c[0] = (_Float16)w3[o * 64 + j];
            c[1] = (_Float16)w3[o * 64 + 32 + j];
            w3p[p] = c;
        }
        if (i < 32) {
            h2 c; c[0] = (_Float16)w4[i]; c[1] = (_Float16)w4[32 + i];
            w4p[i] = c;
        }
        __threadfence();          // device-scope release of weight staging
        return;
    }
    const int i = blockIdx.x * 256 + threadIdx.x;   // float4 index, i < n4
    const f4 v = __builtin_nontemporal_load((const f4*)emb + i);  // single-use
    h4 o;
    o[0] = (_Float16)v[0]; o[1] = (_Float16)v[1];
    o[2] = (_Float16)v[2]; o[3] = (_Float16)v[3];
    ((h4*)tab)[i] = o;            // normal store: tab should allocate in L2
    __threadfence();              // device-scope release of table staging
}

__global__ __launch_bounds__(256, 8) void nnue_fwd(
    const int* __restrict__ x, const _Float16* __restrict__ tab,
    const h2* __restrict__ w2p, const float* __restrict__ b2,
    const h2* __restrict__ w3p, const float* __restrict__ b3,
    const h2* __restrict__ w4p, float* __restrict__ out)
{
    __shared__ h2 lds[64 * STR2];   // 8448 B -> 8+ blocks/CU

    const int t    = threadIdx.x;
    const int lane = t & 63;
    const int g    = lane >> 4;        // lane group = which of 4 rows
    const int sub  = lane & 15;        // 8-dim (4-pair) chunk within a row
    const int row0 = blockIdx.x * 32;
    const int wave = __builtin_amdgcn_readfirstlane(t >> 6);

    // ---------------- Phase 1: gather + packed fp16 sum ----------------
    #pragma unroll
    for (int it = 0; it < 2; ++it) {
        const int rb = wave * 8 + it * 4;            // block-local base row
        const size_t rbase = (size_t)(row0 + rb + g) * 32;
        // x is single-use: non-temporal (keep tab resident in L2)
        const int xv0 = __builtin_nontemporal_load(x + rbase + sub);
        const int xv1 = __builtin_nontemporal_load(x + rbase + 16 + sub);

        h2 accA[4] = {}, accB[4] = {};
        #pragma unroll
        for (int j = 0; j < 29; ++j) {
            const int src = (lane & 48) | (j & 15);  // lane g*16 + (j%16)
            const int idx = __shfl((j < 16) ? xv0 : xv1, src, 64);
            H8 u;
            u.v = *(const h8v*)((const char*)tab +
                                (((unsigned)idx) << 8) + (sub << 4));
            if (j & 1) {
                accB[0] += u.h[0]; accB[1] += u.h[1];
                accB[2] += u.h[2]; accB[3] += u.h[3];
            } else {
                accA[0] += u.h[0]; accA[1] += u.h[1];
                accA[2] += u.h[2]; accA[3] += u.h[3];
            }
        }
        #pragma unroll
        for (int k = 0; k < 4; ++k) {
            const h2 s = h2relu(accA[k] + accB[k]);
            lds[(4 * sub + k) * STR2 + rb + g] = s;  // [pair-dim][row]
        }
    }
    __syncthreads();

    // ---------------- Phase 2: dense layers ----------------
    // lane = row mod 32; both wave-halves compute the same 8 wave-uniform
    // outputs (redundant) so weight loads stay scalar; LDS reads broadcast.
    const int r  = lane & 31;
    const int hf = lane >> 5;
    const int ob = __builtin_amdgcn_readfirstlane((t >> 6) * 8); // 8 outs/wave

    // Layer 2: 128 -> 32 via dot2 over 64 fp16 pairs
    float a2[8];
    #pragma unroll
    for (int oo = 0; oo < 8; ++oo) a2[oo] = b2[ob + oo];
    #pragma unroll 8
    for (int pd = 0; pd < 64; ++pd) {
        const h2 hp = lds[pd * STR2 + r];
        #pragma unroll
        for (int oo = 0; oo < 8; ++oo)
            a2[oo] = __builtin_amdgcn_fdot2(hp, w2p[(ob + oo) * 64 + pd],
                                            a2[oo], false);
    }
    __syncthreads();               // all waves done reading h1
    if (hf == 0) {
        #pragma unroll
        for (int oo = 0; oo < 8; ++oo) {
            h2 c; c[0] = (_Float16)frelu(a2[oo]); c[1] = (_Float16)frelu(-a2[oo]);
            lds[(ob + oo) * STR2 + r] = c;           // c2: pd rows 0..31
        }
    }
    __syncthreads();

    // Layer 3: CReLU(32->64) -> 32 via dot2 on (p,n) pairs
    float a3[8];
    #pragma unroll
    for (int oo = 0; oo < 8; ++oo) a3[oo] = b3[ob + oo];
    #pragma unroll 8
    for (int j = 0; j < 32; ++j) {
        const h2 cp = lds[j * STR2 + r];
        #pragma unroll
        for (int oo = 0; oo < 8; ++oo)
            a3[oo] = __builtin_amdgcn_fdot2(cp, w3p[(ob + oo) * 32 + j],
                                            a3[oo], false);
    }
    // c3 -> pd rows 32..63 (disjoint from c2 reads)
    if (hf == 0) {
        #pragma unroll
        for (int oo = 0; oo < 8; ++oo) {
            h2 c; c[0] = (_Float16)frelu(a3[oo]); c[1] = (_Float16)frelu(-a3[oo]);
            lds[(32 + ob + oo) * STR2 + r] = c;
        }
    }
    __syncthreads();

    // Layer 4: 64 -> 1, lanes 0..31 of wave 0; out is single-use -> nt store
    if (t < 32) {
        float s = 0.f;
        #pragma unroll
        for (int j = 0; j < 32; ++j)
            s = __builtin_amdgcn_fdot2(lds[(32 + j) * STR2 + t], w4p[j], s, false);
        __builtin_nontemporal_store(s, out + row0 + t);
    }
}

extern "C" void kernel_launch(void* const* d_in, const int* in_sizes, int n_in,
                              void* d_out, int out_size, void* d_ws, size_t ws_size,
                              hipStream_t stream) {
    const int*   x   = (const int*)d_in[0];
    const float* emb = (const float*)d_in[1];
    const float* w2  = (const float*)d_in[2];
    const float* b2  = (const float*)d_in[3];
    const float* w3  = (const float*)d_in[4];
    const float* b3  = (const float*)d_in[5];
    const float* w4  = (const float*)d_in[6];
    float* out = (float*)d_out;

    const int emb_elems = in_sizes[1];          // 1,900,544
    const int n_rows    = in_sizes[0] / 32;     // 65536
    const int n4        = emb_elems / 4;        // 475,136 = 1856*256

    char* ws = (char*)d_ws;
    _Float16* tab = (_Float16*)ws;                       // 3,801,088 B
    _Float16* w2p = (_Float16*)(ws + 3801088);           // 8,192 B
    h2*       w3p = (h2*)(ws + 3801088 + 8192);          // 4,096 B
    h2*       w4p = (h2*)(ws + 3801088 + 8192 + 4096);   // 128 B

    hipLaunchKernelGGL(stage, dim3(n4 / 256 + 1), dim3(256), 0, stream,
                       emb, tab, w2, w3, w4, w2p, w3p, w4p, n4);
    hipLaunchKernelGGL(nnue_fwd, dim3(n_rows / 32), dim3(256), 0, stream,
                       x, tab, (const h2*)w2p, b2, w3p, b3, w4p, out);
}

// Round 7
// 104.595 us; speedup vs baseline: 2.3191x; 2.3191x over previous
//
#include <hip/hip_runtime.h>
#include <hip/hip_fp16.h>

// NNUE forward, round 7 = round 6 minus the __threadfence() calls.
// Round 6 showed: (a) per-thread __threadfence() in stage = 150 us disaster
// (device-scope release per wave); (b) the non-temporal hints on x/out are
// worth ~7 us on nnue_fwd (35 -> ~28 us) by keeping the 3.8 MB fp16 table
// resident in the 4 MB per-XCD L2. Kernel-launch ordering on the stream
// already guarantees stage->nnue_fwd visibility (round 4 proved it).

#define STR2 33

using h2  = _Float16 __attribute__((ext_vector_type(2)));
using h4  = _Float16 __attribute__((ext_vector_type(4)));
using h8v = _Float16 __attribute__((ext_vector_type(8)));
using f4  = float __attribute__((ext_vector_type(4)));

union H8 { h8v v; h2 h[4]; };

__device__ __forceinline__ float frelu(float v) { return v > 0.f ? v : 0.f; }

__device__ __forceinline__ h2 h2relu(h2 v) {
    h2 r;
    r[0] = v[0] > (_Float16)0 ? v[0] : (_Float16)0;
    r[1] = v[1] > (_Float16)0 ? v[1] : (_Float16)0;
    return r;
}

// ---- staging: fp32->fp16 table; last block packs the weights ----
__global__ __launch_bounds__(256) void stage(
    const float* __restrict__ emb, _Float16* __restrict__ tab,
    const float* __restrict__ w2, const float* __restrict__ w3,
    const float* __restrict__ w4,
    _Float16* __restrict__ w2p, h2* __restrict__ w3p, h2* __restrict__ w4p,
    int n4) {
    if ((int)blockIdx.x == (int)gridDim.x - 1) {
        const int i = threadIdx.x;
        for (int e = i; e < 32 * 128; e += 256) w2p[e] = (_Float16)w2[e];
        for (int p = i; p < 32 * 32; p += 256) {
            const int o = p >> 5, j = p & 31;
            h2 c; c[0] = (_Float16)w3[o * 64 + j];
            c[1] = (_Float16)w3[o * 64 + 32 + j];
            w3p[p] = c;
        }
        if (i < 32) {
            h2 c; c[0] = (_Float16)w4[i]; c[1] = (_Float16)w4[32 + i];
            w4p[i] = c;
        }
        return;
    }
    const int i = blockIdx.x * 256 + threadIdx.x;   // float4 index, i < n4
    const f4 v = __builtin_nontemporal_load((const f4*)emb + i);  // single-use
    h4 o;
    o[0] = (_Float16)v[0]; o[1] = (_Float16)v[1];
    o[2] = (_Float16)v[2]; o[3] = (_Float16)v[3];
    ((h4*)tab)[i] = o;            // normal store: tab allocates in L2
}

__global__ __launch_bounds__(256, 8) void nnue_fwd(
    const int* __restrict__ x, const _Float16* __restrict__ tab,
    const h2* __restrict__ w2p, const float* __restrict__ b2,
    const h2* __restrict__ w3p, const float* __restrict__ b3,
    const h2* __restrict__ w4p, float* __restrict__ out)
{
    __shared__ h2 lds[64 * STR2];   // 8448 B -> 8+ blocks/CU

    const int t    = threadIdx.x;
    const int lane = t & 63;
    const int g    = lane >> 4;        // lane group = which of 4 rows
    const int sub  = lane & 15;        // 8-dim (4-pair) chunk within a row
    const int row0 = blockIdx.x * 32;
    const int wave = __builtin_amdgcn_readfirstlane(t >> 6);

    // ---------------- Phase 1: gather + packed fp16 sum ----------------
    #pragma unroll
    for (int it = 0; it < 2; ++it) {
        const int rb = wave * 8 + it * 4;            // block-local base row
        const size_t rbase = (size_t)(row0 + rb + g) * 32;
        // x is single-use: non-temporal (keep tab resident in L2)
        const int xv0 = __builtin_nontemporal_load(x + rbase + sub);
        const int xv1 = __builtin_nontemporal_load(x + rbase + 16 + sub);

        h2 accA[4] = {}, accB[4] = {};
        #pragma unroll
        for (int j = 0; j < 29; ++j) {
            const int src = (lane & 48) | (j & 15);  // lane g*16 + (j%16)
            const int idx = __shfl((j < 16) ? xv0 : xv1, src, 64);
            H8 u;
            u.v = *(const h8v*)((const char*)tab +
                                (((unsigned)idx) << 8) + (sub << 4));
            if (j & 1) {
                accB[0] += u.h[0]; accB[1] += u.h[1];
                accB[2] += u.h[2]; accB[3] += u.h[3];
            } else {
                accA[0] += u.h[0]; accA[1] += u.h[1];
                accA[2] += u.h[2]; accA[3] += u.h[3];
            }
        }
        #pragma unroll
        for (int k = 0; k < 4; ++k) {
            const h2 s = h2relu(accA[k] + accB[k]);
            lds[(4 * sub + k) * STR2 + rb + g] = s;  // [pair-dim][row]
        }
    }
    __syncthreads();

    // ---------------- Phase 2: dense layers ----------------
    // lane = row mod 32; both wave-halves compute the same 8 wave-uniform
    // outputs (redundant) so weight loads stay scalar; LDS reads broadcast.
    const int r  = lane & 31;
    const int hf = lane >> 5;
    const int ob = __builtin_amdgcn_readfirstlane((t >> 6) * 8); // 8 outs/wave

    // Layer 2: 128 -> 32 via dot2 over 64 fp16 pairs
    float a2[8];
    #pragma unroll
    for (int oo = 0; oo < 8; ++oo) a2[oo] = b2[ob + oo];
    #pragma unroll 8
    for (int pd = 0; pd < 64; ++pd) {
        const h2 hp = lds[pd * STR2 + r];
        #pragma unroll
        for (int oo = 0; oo < 8; ++oo)
            a2[oo] = __builtin_amdgcn_fdot2(hp, w2p[(ob + oo) * 64 + pd],
                                            a2[oo], false);
    }
    __syncthreads();               // all waves done reading h1
    if (hf == 0) {
        #pragma unroll
        for (int oo = 0; oo < 8; ++oo) {
            h2 c; c[0] = (_Float16)frelu(a2[oo]); c[1] = (_Float16)frelu(-a2[oo]);
            lds[(ob + oo) * STR2 + r] = c;           // c2: pd rows 0..31
        }
    }
    __syncthreads();

    // Layer 3: CReLU(32->64) -> 32 via dot2 on (p,n) pairs
    float a3[8];
    #pragma unroll
    for (int oo = 0; oo < 8; ++oo) a3[oo] = b3[ob + oo];
    #pragma unroll 8
    for (int j = 0; j < 32; ++j) {
        const h2 cp = lds[j * STR2 + r];
        #pragma unroll
        for (int oo = 0; oo < 8; ++oo)
            a3[oo] = __builtin_amdgcn_fdot2(cp, w3p[(ob + oo) * 32 + j],
                                            a3[oo], false);
    }
    // c3 -> pd rows 32..63 (disjoint from c2 reads)
    if (hf == 0) {
        #pragma unroll
        for (int oo = 0; oo < 8; ++oo) {
            h2 c; c[0] = (_Float16)frelu(a3[oo]); c[1] = (_Float16)frelu(-a3[oo]);
            lds[(32 + ob + oo) * STR2 + r] = c;
        }
    }
    __syncthreads();

    // Layer 4: 64 -> 1, lanes 0..31 of wave 0; out is single-use -> nt store
    if (t < 32) {
        float s = 0.f;
        #pragma unroll
        for (int j = 0; j < 32; ++j)
            s = __builtin_amdgcn_fdot2(lds[(32 + j) * STR2 + t], w4p[j], s, false);
        __builtin_nontemporal_store(s, out + row0 + t);
    }
}

extern "C" void kernel_launch(void* const* d_in, const int* in_sizes, int n_in,
                              void* d_out, int out_size, void* d_ws, size_t ws_size,
                              hipStream_t stream) {
    const int*   x   = (const int*)d_in[0];
    const float* emb = (const float*)d_in[1];
    const float* w2  = (const float*)d_in[2];
    const float* b2  = (const float*)d_in[3];
    const float* w3  = (const float*)d_in[4];
    const float* b3  = (const float*)d_in[5];
    const float* w4  = (const float*)d_in[6];
    float* out = (float*)d_out;

    const int emb_elems = in_sizes[1];          // 1,900,544
    const int n_rows    = in_sizes[0] / 32;     // 65536
    const int n4        = emb_elems / 4;        // 475,136 = 1856*256

    char* ws = (char*)d_ws;
    _Float16* tab = (_Float16*)ws;                       // 3,801,088 B
    _Float16* w2p = (_Float16*)(ws + 3801088);           // 8,192 B
    h2*       w3p = (h2*)(ws + 3801088 + 8192);          // 4,096 B
    h2*       w4p = (h2*)(ws + 3801088 + 8192 + 4096);   // 128 B

    hipLaunchKernelGGL(stage, dim3(n4 / 256 + 1), dim3(256), 0, stream,
                       emb, tab, w2, w3, w4, w2p, w3p, w4p, n4);
    hipLaunchKernelGGL(nnue_fwd, dim3(n_rows / 32), dim3(256), 0, stream,
                       x, tab, (const h2*)w2p, b2, w3p, b3, w4p, out);
}